// Round 16
// baseline (121.757 us; speedup 1.0000x reference)
//
#include <hip/hip_runtime.h>
#include <math.h>

// AutoregressiveFlowLayer MI355X — round 25.
// R24 post-mortem (43.5us best): conflict-volume cut 6.3->5.1M but dur only
// -4% -> LDS throughput is a cost, not the critical path. Bank geometry
// re-derived: 272B stride covers all 32 banks uniformly; counter mostly counts
// inherent b128 wave64 serialization. Remaining wait (~35-40% of wall) sits in
// barrier drains + latency with only 2 independent streams/CU.
// R25 = SAME dataflow, 256-thread blocks: barrier group 8 waves -> 4, streams
// 2 -> 4 per CU (when one block drains, three fill the SIMDs). Per-wave
// instruction stream identical to R24 (wave mq owns 32 P1/P2 cols, 16 P3
// o-cols). ao[4] back in registers (free in the 128-reg bin at (256,4)) ->
// P3's wout ds_reads deleted (-20% LDS read volume). TROWS=32, 8 tiles,
// grid 32x32=1024 = 4 blocks/CU, 16 waves/CU (same TLP). LDS 23.4KB x4 = 94KB.
// Predict: 43.5 -> 37-41us; conflicts ~4M; VGPR 100-120, WRITE ~1.2MB (spill
// check). If 43+-2: serial interval floor is intrinsic -> declare ceiling.

#define RR 32
#define DD 1024
#define HH 128
#define OO 64
#define TROWS 32
#define TILES 8
#define BLOCKS_PER_R 32

#define SHP 136   // u16 stride, h planes [row][feat]
#define SXG 40    // u16 stride, xg plane [row][feat]
#define SSC 136   // u16 stride, weight staging [col][k], K=128
#define SW1 40    // u16 stride, W1 staging [col][k], K=32

typedef _Float16 f16x8_t __attribute__((ext_vector_type(8)));
typedef float f32x4_t __attribute__((ext_vector_type(4)));
typedef unsigned short u16;
typedef unsigned int u32;

__device__ __forceinline__ u32 pkrtz(float a, float b) {
    union { __fp16 v __attribute__((ext_vector_type(2))); u32 u; } c;
    c.v = __builtin_amdgcn_cvt_pkrtz(a, b);
    return c.u;
}
__device__ __forceinline__ f32x4_t mfma16h(f16x8_t a, f16x8_t b, f32x4_t c) {
    return __builtin_amdgcn_mfma_f32_16x16x32_f16(a, b, c, 0, 0, 0);
}

// stage [K x 32] weight slice (row-major [k][col], ld ldc, col offset c0) into
// fp16 [col][k] scratch (k-stride sd), conflict-free 4x4 transpose. tid in [0,256).
__device__ __forceinline__ void stage_block16(const float* __restrict__ W,
                                              const int* __restrict__ M,
                                              int ldc, int c0, int K,
                                              u16* dst, int sd, int tid)
{
    const int kb = tid >> 3;
    const int cb = tid & 7;
    if (kb * 4 >= K) return;
    const int k0 = kb * 4;
    float e[4][4];
#pragma unroll
    for (int i = 0; i < 4; ++i) {
        const int o = ((k0 + i) * ldc + c0 + 4 * cb) >> 2;
        float4 w = ((const float4*)W)[o];
        int4   m = ((const int4*)M)[o];
        e[i][0] = m.x ? w.x : 0.f; e[i][1] = m.y ? w.y : 0.f;
        e[i][2] = m.z ? w.z : 0.f; e[i][3] = m.w ? w.w : 0.f;
    }
#pragma unroll
    for (int j = 0; j < 4; ++j) {
        uint2 p;
        p.x = pkrtz(e[0][j], e[1][j]);
        p.y = pkrtz(e[2][j], e[3][j]);
        *(uint2*)&dst[(4 * cb + j) * sd + k0] = p;
    }
}

// ReLU + fp16 pack of 4 accumulator values, one 8B store.
__device__ __forceinline__ void relu_store16(u16* __restrict__ dst, int o, f32x4_t a)
{
    uint2 s;
    s.x = pkrtz(fmaxf(a[0], 0.f), fmaxf(a[1], 0.f));
    s.y = pkrtz(fmaxf(a[2], 0.f), fmaxf(a[3], 0.f));
    *(uint2*)&dst[o] = s;
}

__global__ __launch_bounds__(256, 4)
void made_flow_r25(const float* __restrict__ inputs,
                   const float* __restrict__ W1,
                   const float* __restrict__ W2,
                   const float* __restrict__ Wout,
                   const int* __restrict__ idx,
                   const int* __restrict__ valid,
                   const int* __restrict__ M1,
                   const int* __restrict__ M2,
                   const int* __restrict__ Mout,
                   float* __restrict__ out)
{
    __shared__ __align__(16) u16 h1s[TROWS * SHP];      // 8704 B (staging scratch A)
    __shared__ __align__(16) u16 h2s[TROWS * SHP];      // 8704 B (staging scratch B)
    __shared__ __align__(16) u16 xgh[2][TROWS * SXG];   // 5120 B
    __shared__ __align__(16) float red2[2][TROWS][4];   // 1024 B
    __shared__ int   idx_s[RR];
    __shared__ float v_s[RR];
    // total ~23.4 KB -> 4 blocks/CU (reg-limited at 128)

    u16* const scr  = h1s;
    u16* const scr2 = h2s;

    const int tid  = threadIdx.x;
    const int r    = blockIdx.x / BLOCKS_PER_R;
    const int rb   = blockIdx.x % BLOCKS_PER_R;
    const int ts   = rb * TILES;

    const int lane = tid & 63;
    const int wave = tid >> 6;     // 0..3
    const int q    = lane >> 4;
    const int l16  = lane & 15;
    const int mq   = wave;         // P1/P2: col group 32*mq; P3: o-col group 16*mq

    if (tid < RR) {
        idx_s[tid] = idx[r * RR + tid];
        v_s[tid]   = valid[r * RR + tid] ? 1.f : 0.f;
    }

    // ---- stage weights -> per-wave register frags (a1[2], a2[2][4], ao[4]) ----
    f16x8_t a1[2];      // W1^T: cols 32mq+16mi+l16, k=q*8..
    f16x8_t a2[2][4];   // W2^T: [mi][ks], cols 32mq+16mi+l16
    f16x8_t ao[4];      // Wout^T: [ks], o-cols 16mq+l16
    {
        const float* W1r = W1 + r * RR * HH;   const int* M1r = M1 + r * RR * HH;
        const float* W2r = W2 + r * HH * HH;   const int* M2r = M2 + r * HH * HH;
        const float* Wor = Wout + r * HH * OO; const int* Mor = Mout + r * HH * OO;
        // W2: 4 chunks of 32 cols, one per round; wave mq extracts chunk mq
        for (int c = 0; c < 4; ++c) {
            __syncthreads();
            stage_block16(W2r, M2r, HH, 32 * c, HH, scr, SSC, tid);
            __syncthreads();
            if (mq == c) {
#pragma unroll
                for (int mi = 0; mi < 2; ++mi)
#pragma unroll
                    for (int ks = 0; ks < 4; ++ks)
                        a2[mi][ks] = *(const f16x8_t*)&scr[(16 * mi + l16) * SSC + ks * 32 + q * 8];
            }
        }
        // Wout: 2 chunks; waves 0,1 extract from chunk 0, waves 2,3 from chunk 1
        for (int c = 0; c < 2; ++c) {
            __syncthreads();
            stage_block16(Wor, Mor, OO, 32 * c, HH, scr, SSC, tid);
            __syncthreads();
            if ((wave >> 1) == c) {
#pragma unroll
                for (int ks = 0; ks < 4; ++ks)
                    ao[ks] = *(const f16x8_t*)&scr[(16 * (wave & 1) + l16) * SSC + ks * 32 + q * 8];
            }
        }
        // W1 (K=32): all 4 chunks in ONE round by 64-thread groups;
        // chunks 0,1 -> scr rows 0..63, chunks 2,3 -> scr2 rows 0..63
        __syncthreads();
        {
            const int c  = tid >> 6;        // 0..3
            const int tp = tid & 63;
            u16* dst = (c < 2 ? scr : scr2) + 32 * (c & 1) * SW1;
            stage_block16(W1r, M1r, HH, 32 * c, RR, dst, SW1, tp);
        }
        __syncthreads();
        {
            const u16* s = (mq < 2) ? scr : scr2;
#pragma unroll
            for (int mi = 0; mi < 2; ++mi)
                a1[mi] = *(const f16x8_t*)&s[(32 * (mq & 1) + 16 * mi + l16) * SW1 + q * 8];
        }
    }
    __syncthreads();   // staging reads done before xg/h1 writes

    const f32x4_t zero4 = {0.f, 0.f, 0.f, 0.f};
    const int grow = tid >> 3;     // 0..31 batch row (gather role)
    const int gg   = tid & 7;      // col quad: 4*gg..4*gg+3
    int   ci[4]; float cv[4];
#pragma unroll
    for (int u = 0; u < 4; ++u) {
        ci[u] = idx_s[4 * gg + u];
        cv[u] = v_s[4 * gg + u];
    }
    const int j0  = 8 * mq + 2 * q;                    // epilogue cols
    const float vj0 = v_s[j0], vj1 = v_s[j0 + 1];
    const int gbase = (ts * TROWS + grow) * DD;

    // ---- prologue: gather(0) -> xgh[0]; issue gather(1) into regs ----
    float gx[4];
    {
        float a0 = inputs[gbase + ci[0]] * cv[0];
        float a1v = inputs[gbase + ci[1]] * cv[1];
        float a2v = inputs[gbase + ci[2]] * cv[2];
        float a3 = inputs[gbase + ci[3]] * cv[3];
        uint2 p; p.x = pkrtz(a0, a1v); p.y = pkrtz(a2v, a3);
        *(uint2*)&xgh[0][grow * SXG + 4 * gg] = p;
#pragma unroll
        for (int u = 0; u < 4; ++u)
            gx[u] = inputs[gbase + TROWS * DD + ci[u]] * cv[u];
    }
    __syncthreads();

    // ---- prologue: P1(0) -> h1s (wave owns cols 32mq..+32) ----
    {
#pragma unroll
        for (int ni = 0; ni < 2; ++ni) {
            const int rw = 16 * ni + l16;
            f16x8_t b = *(const f16x8_t*)&xgh[0][rw * SXG + q * 8];
#pragma unroll
            for (int mi = 0; mi < 2; ++mi) {
                f32x4_t a = mfma16h(a1[mi], b, zero4);
                relu_store16(h1s, rw * SHP + 32 * mq + 16 * mi + 4 * q, a);
            }
        }
    }

    for (int t = 0; t < TILES; ++t) {
        __syncthreads();   // head barrier

        const bool dg = (t + 1 < TILES);

        // ========== interval A: gather-store(t+1) + P2(t) + out-store(t-2) ========
        if (dg) {
            uint2 p; p.x = pkrtz(gx[0], gx[1]); p.y = pkrtz(gx[2], gx[3]);
            *(uint2*)&xgh[(t + 1) & 1][grow * SXG + 4 * gg] = p;
        }
        {
            // P2(t): wave owns cols 32mq..+32, both ni; 16 MFMA, 8 B-reads
            f32x4_t acc[2][2] = {{zero4, zero4}, {zero4, zero4}};
            __builtin_amdgcn_s_setprio(1);
#pragma unroll
            for (int ks = 0; ks < 4; ++ks) {
#pragma unroll
                for (int ni = 0; ni < 2; ++ni) {
                    f16x8_t b = *(const f16x8_t*)&h1s[(16 * ni + l16) * SHP + ks * 32 + q * 8];
#pragma unroll
                    for (int mi = 0; mi < 2; ++mi)
                        acc[mi][ni] = mfma16h(a2[mi][ks], b, acc[mi][ni]);
                }
            }
            __builtin_amdgcn_s_setprio(0);
#pragma unroll
            for (int mi = 0; mi < 2; ++mi)
#pragma unroll
                for (int ni = 0; ni < 2; ++ni)
                    relu_store16(h2s, (16 * ni + l16) * SHP + 32 * mq + 16 * mi + 4 * q,
                                 acc[mi][ni]);
        }
        if (t >= 2 && tid < TROWS) {
            float4 rv = *(const float4*)&red2[t & 1][tid][0];
            out[((ts + (t - 2)) * TROWS + tid) * RR + r] =
                rv.x + rv.y + rv.z + rv.w;
        }
        __syncthreads();   // mid barrier

        // ========== interval B: gather-issue(t+2) + P3(t) + P1(t+1) + epilogue(t) ==
        if (t + 2 < TILES) {
            const int base = gbase + (t + 2) * (TROWS * DD);
#pragma unroll
            for (int u = 0; u < 4; ++u)
                gx[u] = inputs[base + ci[u]] * cv[u];
        }

        // P3(t): wave owns o-cols 16mq..+16, both ni; 8 MFMA, 8 B-reads, A in regs
        f32x4_t acc3[2] = {zero4, zero4};
        __builtin_amdgcn_s_setprio(1);
#pragma unroll
        for (int ks = 0; ks < 4; ++ks) {
#pragma unroll
            for (int ni = 0; ni < 2; ++ni) {
                f16x8_t b = *(const f16x8_t*)&h2s[(16 * ni + l16) * SHP + ks * 32 + q * 8];
                acc3[ni] = mfma16h(ao[ks], b, acc3[ni]);
            }
        }
        __builtin_amdgcn_s_setprio(0);

        if (dg) {   // P1(t+1)
#pragma unroll
            for (int ni = 0; ni < 2; ++ni) {
                const int rw = 16 * ni + l16;
                f16x8_t b = *(const f16x8_t*)&xgh[(t + 1) & 1][rw * SXG + q * 8];
#pragma unroll
                for (int mi = 0; mi < 2; ++mi) {
                    f32x4_t a = mfma16h(a1[mi], b, zero4);
                    relu_store16(h1s, rw * SHP + 32 * mq + 16 * mi + 4 * q, a);
                }
            }
        }

        // epilogue(t): acc3[ni][i]: i even=shift(j), i odd=log_s(j), j=8mq+2q+(i>>1)
#pragma unroll
        for (int ni = 0; ni < 2; ++ni) {
            const int row = 16 * ni + l16;
            u32 xw = *(const u32*)&xgh[t & 1][row * SXG + j0];
            union { u32 u; _Float16 h[2]; } xc; xc.u = xw;
            const float xv0 = (float)xc.h[0], xv1 = (float)xc.h[1];
            f32x4_t a = acc3[ni];
            const float u0 = (xv0 - a[0]) * __expf(-a[1]);
            const float u1 = (xv1 - a[2]) * __expf(-a[3]);
            float p = (-0.5f * u0 * u0 - 0.91893853320467266954f - a[1]) * vj0
                    + (-0.5f * u1 * u1 - 0.91893853320467266954f - a[3]) * vj1;
            p += __shfl_xor(p, 16, 64);
            p += __shfl_xor(p, 32, 64);
            if (q == 0) red2[t & 1][row][mq] = p;
        }
    }

    // ---- tail: store tiles TILES-2 and TILES-1 ----
    __syncthreads();
    if (tid < 2 * TROWS) {
        const int tt  = TILES - 2 + (tid >> 5);
        const int row = tid & 31;
        float4 rv = *(const float4*)&red2[tt & 1][row][0];
        out[((ts + tt) * TROWS + row) * RR + r] =
            rv.x + rv.y + rv.z + rv.w;
    }
}

extern "C" void kernel_launch(void* const* d_in, const int* in_sizes, int n_in,
                              void* d_out, int out_size, void* d_ws, size_t ws_size,
                              hipStream_t stream)
{
    const float* inputs = (const float*)d_in[0];
    const float* W1     = (const float*)d_in[1];
    const float* W2     = (const float*)d_in[2];
    const float* Wout   = (const float*)d_in[3];
    const int*   idx    = (const int*)d_in[4];
    const int*   valid  = (const int*)d_in[5];
    const int*   M1     = (const int*)d_in[6];
    const int*   M2     = (const int*)d_in[7];
    const int*   Mout   = (const int*)d_in[8];
    float*       out    = (float*)d_out;

    hipLaunchKernelGGL(made_flow_r25, dim3(RR * BLOCKS_PER_R), dim3(256), 0, stream,
                       inputs, W1, W2, Wout, idx, valid, M1, M2, Mout, out);
}

// Round 17
// 118.940 us; speedup vs baseline: 1.0237x; 1.0237x over previous
//
#include <hip/hip_runtime.h>
#include <math.h>

// AutoregressiveFlowLayer MI355X — round 26.
// R25 post-mortem (REGRESSION 48-51us): 256-thread repackaging lost residency
// (occ 31%, scheduler doesn't co-locate 4 small blocks/CU) and doubled weight
// re-fetch (FETCH 45->58MB). Reverted to R24 champion (43.5us).
// R26 = R24 + full-tile gather cover (the unapplied half of T14):
//   R24 issued gather(t+1) at top of B(t) and consumed it as the FIRST op of
//   A(t+1) — ~1-2K cy cover vs ~900+cy scattered-load latency; the compiler's
//   vmcnt(0) stalls the wave BEFORE P2 starts. Now: interval A = {store
//   xgh(t+1) [covered by a FULL tile], issue gather(t+2), P2, out-store};
//   interval B = pure P3+P1+epilogue. Buffer audit unchanged (xgh 2-deep ok:
//   plane t&1 rewritten at A(t+1) after epilogue(t) read in B(t)).
// Everything else byte-identical to R24: TROWS=64, M4xN2 split, a1[2]/a2[2][4]
// regs, wout_lds resident, pkrtz, setprio, red2 rolling store, (512,4).
// Predict: 43.5 -> 40-43us; other counters unchanged. If delta <=1us: cover was
// sufficient -> 43us is this dataflow family's floor; declare next round.

#define RR 32
#define DD 1024
#define HH 128
#define OO 64
#define TROWS 64
#define TILES 8
#define BLOCKS_PER_R 16

#define SHP 136   // u16 stride, h planes [row][feat]
#define SXG 40    // u16 stride, xg plane [row][feat]
#define SSC 136   // u16 stride, weight staging / wout_lds [col][k]

typedef _Float16 f16x8_t __attribute__((ext_vector_type(8)));
typedef float f32x4_t __attribute__((ext_vector_type(4)));
typedef unsigned short u16;
typedef unsigned int u32;

__device__ __forceinline__ u32 pkrtz(float a, float b) {
    union { __fp16 v __attribute__((ext_vector_type(2))); u32 u; } c;
    c.v = __builtin_amdgcn_cvt_pkrtz(a, b);
    return c.u;
}
__device__ __forceinline__ f32x4_t mfma16h(f16x8_t a, f16x8_t b, f32x4_t c) {
    return __builtin_amdgcn_mfma_f32_16x16x32_f16(a, b, c, 0, 0, 0);
}

// stage [K x 32] weight slice (row-major [k][col], ld ldc, col offset c0) into
// fp16 [col][k] scratch (stride SSC), conflict-free 4x4 transpose. tid in [0,256).
__device__ __forceinline__ void stage_block16(const float* __restrict__ W,
                                              const int* __restrict__ M,
                                              int ldc, int c0, int K, u16* dst,
                                              int tid)
{
    const int kb = tid >> 3;
    const int cb = tid & 7;
    if (kb * 4 >= K) return;
    const int k0 = kb * 4;
    float e[4][4];
#pragma unroll
    for (int i = 0; i < 4; ++i) {
        const int o = ((k0 + i) * ldc + c0 + 4 * cb) >> 2;
        float4 w = ((const float4*)W)[o];
        int4   m = ((const int4*)M)[o];
        e[i][0] = m.x ? w.x : 0.f; e[i][1] = m.y ? w.y : 0.f;
        e[i][2] = m.z ? w.z : 0.f; e[i][3] = m.w ? w.w : 0.f;
    }
#pragma unroll
    for (int j = 0; j < 4; ++j) {
        uint2 p;
        p.x = pkrtz(e[0][j], e[1][j]);
        p.y = pkrtz(e[2][j], e[3][j]);
        *(uint2*)&dst[(4 * cb + j) * SSC + k0] = p;
    }
}

// ReLU + fp16 pack of 4 accumulator values, one 8B store.
__device__ __forceinline__ void relu_store16(u16* __restrict__ dst, int o, f32x4_t a)
{
    uint2 s;
    s.x = pkrtz(fmaxf(a[0], 0.f), fmaxf(a[1], 0.f));
    s.y = pkrtz(fmaxf(a[2], 0.f), fmaxf(a[3], 0.f));
    *(uint2*)&dst[o] = s;
}

__global__ __launch_bounds__(512, 4)
void made_flow_r26(const float* __restrict__ inputs,
                   const float* __restrict__ W1,
                   const float* __restrict__ W2,
                   const float* __restrict__ Wout,
                   const int* __restrict__ idx,
                   const int* __restrict__ valid,
                   const int* __restrict__ M1,
                   const int* __restrict__ M2,
                   const int* __restrict__ Mout,
                   float* __restrict__ out)
{
    __shared__ __align__(16) u16 h1s[TROWS * SHP];      // 17408 B (staging scratch A)
    __shared__ __align__(16) u16 h2s[TROWS * SHP];      // 17408 B (staging scratch B)
    __shared__ __align__(16) u16 wout_lds[OO * SSC];    // 17408 B (Wout^T resident)
    __shared__ __align__(16) u16 xgh[2][TROWS * SXG];   // 10240 B
    __shared__ __align__(16) float red2[2][TROWS][4];   // 2048 B
    __shared__ int   idx_s[RR];
    __shared__ float v_s[RR];
    // total ~64.8 KB -> 2 blocks/CU

    u16* const scr  = h1s;
    u16* const scr2 = h2s;

    const int tid  = threadIdx.x;
    const int r    = blockIdx.x / BLOCKS_PER_R;
    const int rb   = blockIdx.x % BLOCKS_PER_R;
    const int ts64 = rb * TILES * TROWS;     // first batch row of this block

    const int lane = tid & 63;
    const int wave = tid >> 6;     // 0..7
    const int q    = lane >> 4;
    const int l16  = lane & 15;
    const int mq   = wave & 3;     // P1/P2: col group 32*mq
    const int nh   = wave >> 2;    // P1/P2: ni pair {2nh, 2nh+1}
    const int wm3  = wave & 3;     // P3: o-col group 16*wm3
    const int ni3  = wave >> 2;    // P3: batch-row quarter base (ni3, ni3+2)

    if (tid < RR) {
        idx_s[tid] = idx[r * RR + tid];
        v_s[tid]   = valid[r * RR + tid] ? 1.f : 0.f;
    }

    // ---- stage weights: a1[2], a2[2][4] -> regs; Wout^T -> resident LDS ----
    f16x8_t a1[2];      // W1^T: cols 32mq+16mi+l16, k=q*8..
    f16x8_t a2[2][4];   // W2^T: [mi][ks], cols 32mq+16mi+l16
    {
        const float* W1r = W1 + r * RR * HH;   const int* M1r = M1 + r * RR * HH;
        const float* W2r = W2 + r * HH * HH;   const int* M2r = M2 + r * HH * HH;
        const float* Wor = Wout + r * HH * OO; const int* Mor = Mout + r * HH * OO;
        for (int i = 0; i < 2; ++i) {
            __syncthreads();
            if (tid < 256) stage_block16(W2r, M2r, HH, 32 * (2 * i),     HH, scr,  tid);
            else           stage_block16(W2r, M2r, HH, 32 * (2 * i + 1), HH, scr2, tid - 256);
            __syncthreads();
            if (mq == 2 * i) {
#pragma unroll
                for (int mi = 0; mi < 2; ++mi)
#pragma unroll
                    for (int ks = 0; ks < 4; ++ks)
                        a2[mi][ks] = *(const f16x8_t*)&scr[(16 * mi + l16) * SSC + ks * 32 + q * 8];
            } else if (mq == 2 * i + 1) {
#pragma unroll
                for (int mi = 0; mi < 2; ++mi)
#pragma unroll
                    for (int ks = 0; ks < 4; ++ks)
                        a2[mi][ks] = *(const f16x8_t*)&scr2[(16 * mi + l16) * SSC + ks * 32 + q * 8];
            }
        }
        for (int i = 0; i < 2; ++i) {
            __syncthreads();
            if (tid < 256) stage_block16(W1r, M1r, HH, 32 * (2 * i),     RR, scr,  tid);
            else           stage_block16(W1r, M1r, HH, 32 * (2 * i + 1), RR, scr2, tid - 256);
            __syncthreads();
            if (mq == 2 * i) {
#pragma unroll
                for (int mi = 0; mi < 2; ++mi)
                    a1[mi] = *(const f16x8_t*)&scr [(16 * mi + l16) * SSC + q * 8];
            } else if (mq == 2 * i + 1) {
#pragma unroll
                for (int mi = 0; mi < 2; ++mi)
                    a1[mi] = *(const f16x8_t*)&scr2[(16 * mi + l16) * SSC + q * 8];
            }
        }
        // Wout^T -> wout_lds (read-only for the rest of the kernel)
        if (tid < 256) stage_block16(Wor, Mor, OO, 0,  HH, wout_lds,            tid);
        else           stage_block16(Wor, Mor, OO, 32, HH, wout_lds + 32 * SSC, tid - 256);
    }
    __syncthreads();   // staging done before xg/h1 writes; idx_s/v_s visible

    const f32x4_t zero4 = {0.f, 0.f, 0.f, 0.f};
    const int grow = tid >> 4;     // 0..31 (gather rows grow and grow+32)
    const int gg   = tid & 15;     // col pair: 2*gg, 2*gg+1
    const int   ci0 = idx_s[2 * gg], ci1 = idx_s[2 * gg + 1];
    const float cv0 = v_s[2 * gg],   cv1 = v_s[2 * gg + 1];
    const int j0  = 8 * wm3 + 2 * q;                    // epilogue cols
    const float vj0 = v_s[j0], vj1 = v_s[j0 + 1];
    const int gb0 = (ts64 + grow) * DD;
    const int gb1 = (ts64 + 32 + grow) * DD;

    // ---- prologue: gather(0) -> xgh[0]; issue gather(1) into regs ----
    float gx[4];
    {
        float a0 = inputs[gb0 + ci0] * cv0, a1v = inputs[gb0 + ci1] * cv1;
        float b0 = inputs[gb1 + ci0] * cv0, b1v = inputs[gb1 + ci1] * cv1;
        *(u32*)&xgh[0][grow * SXG + 2 * gg]        = pkrtz(a0, a1v);
        *(u32*)&xgh[0][(grow + 32) * SXG + 2 * gg] = pkrtz(b0, b1v);
        gx[0] = inputs[gb0 + TROWS * DD + ci0] * cv0;
        gx[1] = inputs[gb0 + TROWS * DD + ci1] * cv1;
        gx[2] = inputs[gb1 + TROWS * DD + ci0] * cv0;
        gx[3] = inputs[gb1 + TROWS * DD + ci1] * cv1;
    }
    __syncthreads();

    // ---- prologue: P1(0) -> h1s (M4xN2 split) ----
    {
#pragma unroll
        for (int nn = 0; nn < 2; ++nn) {
            const int rw = 16 * (2 * nh + nn) + l16;
            f16x8_t b = *(const f16x8_t*)&xgh[0][rw * SXG + q * 8];
#pragma unroll
            for (int mi = 0; mi < 2; ++mi) {
                f32x4_t a = mfma16h(a1[mi], b, zero4);
                relu_store16(h1s, rw * SHP + 32 * mq + 16 * mi + 4 * q, a);
            }
        }
    }

    for (int t = 0; t < TILES; ++t) {
        __syncthreads();   // head barrier

        const bool dg = (t + 1 < TILES);

        // ========== interval A: xgh-store(t+1) [full-tile-covered] +
        //            gather-issue(t+2) + P2(t) + out-store(t-2) ==================
        if (dg) {
            // consumes gx issued at A(t-1) (prologue for t=0): one full tile of cover
            *(u32*)&xgh[(t + 1) & 1][grow * SXG + 2 * gg]        = pkrtz(gx[0], gx[1]);
            *(u32*)&xgh[(t + 1) & 1][(grow + 32) * SXG + 2 * gg] = pkrtz(gx[2], gx[3]);
        }
        if (t + 2 < TILES) {
            // issue next gather immediately: consumed at A(t+1)
            const int base = (t + 2) * (TROWS * DD);
            gx[0] = inputs[gb0 + base + ci0] * cv0;
            gx[1] = inputs[gb0 + base + ci1] * cv1;
            gx[2] = inputs[gb1 + base + ci0] * cv0;
            gx[3] = inputs[gb1 + base + ci1] * cv1;
        }
        {
            // P2(t): wave owns cols 32mq..+32, rows ni=2nh,2nh+1; 16 MFMA, 8 B-reads
            f32x4_t acc[2][2] = {{zero4, zero4}, {zero4, zero4}};
            __builtin_amdgcn_s_setprio(1);
#pragma unroll
            for (int ks = 0; ks < 4; ++ks) {
#pragma unroll
                for (int nn = 0; nn < 2; ++nn) {
                    f16x8_t b = *(const f16x8_t*)&h1s[(16 * (2 * nh + nn) + l16) * SHP + ks * 32 + q * 8];
#pragma unroll
                    for (int mi = 0; mi < 2; ++mi)
                        acc[mi][nn] = mfma16h(a2[mi][ks], b, acc[mi][nn]);
                }
            }
            __builtin_amdgcn_s_setprio(0);
#pragma unroll
            for (int mi = 0; mi < 2; ++mi)
#pragma unroll
                for (int nn = 0; nn < 2; ++nn)
                    relu_store16(h2s, (16 * (2 * nh + nn) + l16) * SHP + 32 * mq + 16 * mi + 4 * q,
                                 acc[mi][nn]);
        }
        if (t >= 2 && tid < TROWS) {
            float4 rv = *(const float4*)&red2[t & 1][tid][0];
            out[((rb * TILES + (t - 2)) * TROWS + tid) * RR + r] =
                rv.x + rv.y + rv.z + rv.w;
        }
        __syncthreads();   // mid barrier

        // ========== interval B: P3(t) + P1(t+1) + epilogue(t) =====================
        // P3(t): wave (wm3,ni3): o=16*wm3+4q+i, rows 16*(ni3+2*nn)+l16
        f32x4_t acc3[2] = {zero4, zero4};
        __builtin_amdgcn_s_setprio(1);
#pragma unroll
        for (int ks = 0; ks < 4; ++ks) {
            f16x8_t ao = *(const f16x8_t*)&wout_lds[(16 * wm3 + l16) * SSC + ks * 32 + q * 8];
#pragma unroll
            for (int nn = 0; nn < 2; ++nn) {
                f16x8_t b = *(const f16x8_t*)&h2s[(16 * (ni3 + 2 * nn) + l16) * SHP + ks * 32 + q * 8];
                acc3[nn] = mfma16h(ao, b, acc3[nn]);
            }
        }
        __builtin_amdgcn_s_setprio(0);

        if (dg) {   // P1(t+1): M4xN2 split
#pragma unroll
            for (int nn = 0; nn < 2; ++nn) {
                const int rw = 16 * (2 * nh + nn) + l16;
                f16x8_t b = *(const f16x8_t*)&xgh[(t + 1) & 1][rw * SXG + q * 8];
#pragma unroll
                for (int mi = 0; mi < 2; ++mi) {
                    f32x4_t a = mfma16h(a1[mi], b, zero4);
                    relu_store16(h1s, rw * SHP + 32 * mq + 16 * mi + 4 * q, a);
                }
            }
        }

        // epilogue(t): acc3[nn][i]: i even=shift(j), i odd=log_s(j), j=8*wm3+2q+(i>>1)
#pragma unroll
        for (int nn = 0; nn < 2; ++nn) {
            const int row = 16 * (ni3 + 2 * nn) + l16;
            u32 xw = *(const u32*)&xgh[t & 1][row * SXG + j0];
            union { u32 u; _Float16 h[2]; } xc; xc.u = xw;
            const float xv0 = (float)xc.h[0], xv1 = (float)xc.h[1];
            f32x4_t a = acc3[nn];
            const float u0 = (xv0 - a[0]) * __expf(-a[1]);
            const float u1 = (xv1 - a[2]) * __expf(-a[3]);
            float p = (-0.5f * u0 * u0 - 0.91893853320467266954f - a[1]) * vj0
                    + (-0.5f * u1 * u1 - 0.91893853320467266954f - a[3]) * vj1;
            p += __shfl_xor(p, 16, 64);
            p += __shfl_xor(p, 32, 64);
            if (q == 0) red2[t & 1][row][wm3] = p;
        }
    }

    // ---- tail: store tiles TILES-2 and TILES-1 ----
    __syncthreads();
    if (tid < 2 * TROWS) {
        const int tt  = TILES - 2 + (tid >> 6);
        const int row = tid & 63;
        float4 rv = *(const float4*)&red2[tt & 1][row][0];
        out[((rb * TILES + tt) * TROWS + row) * RR + r] =
            rv.x + rv.y + rv.z + rv.w;
    }
}

extern "C" void kernel_launch(void* const* d_in, const int* in_sizes, int n_in,
                              void* d_out, int out_size, void* d_ws, size_t ws_size,
                              hipStream_t stream)
{
    const float* inputs = (const float*)d_in[0];
    const float* W1     = (const float*)d_in[1];
    const float* W2     = (const float*)d_in[2];
    const float* Wout   = (const float*)d_in[3];
    const int*   idx    = (const int*)d_in[4];
    const int*   valid  = (const int*)d_in[5];
    const int*   M1     = (const int*)d_in[6];
    const int*   M2     = (const int*)d_in[7];
    const int*   Mout   = (const int*)d_in[8];
    float*       out    = (float*)d_out;

    hipLaunchKernelGGL(made_flow_r26, dim3(RR * BLOCKS_PER_R), dim3(512), 0, stream,
                       inputs, W1, W2, Wout, idx, valid, M1, M2, Mout, out);
}

// Round 18
// 117.055 us; speedup vs baseline: 1.0402x; 1.0161x over previous
//
#include <hip/hip_runtime.h>
#include <math.h>

// AutoregressiveFlowLayer MI355X — round 27.
// R26 post-mortem (46.2-48.2, slight REGRESSION vs R24 42.7-45.8): full-tile
// gather cover extended live-ranges and helped nothing — gather latency was
// already covered. Intra-loop latency levers exhausted (17 variants; all pipes
// <=25%; 128-reg bin caps 16 waves/CU). Champion R24 restored byte-identical.
// R27 attacks the only un-attacked cost: OUTSIDE-loop overhead.
//  (1) Compact preamble: extraction of W2 pair k overlaps staging of a
//      DIFFERENT LDS region in the same round (E01 || Wout->wout_lds;
//      E23 || W1->xgh-scratch, W1 4-chunks-in-one-round by 64-thread groups).
//      10 barriers -> 6; 5 latency rounds -> 3. ~1-1.5us/block.
//  (2) gather(0)+(1) issued at kernel TOP (per-lane idx/valid direct from
//      global): scatter latency hides under the whole preamble. xgh[0] stored
//      after W1 extraction frees the xgh scratch.
//  (3) epilogue xw LDS reads hoisted above P3's MFMA loop.
// Predict: 43.5 -> 41-43us; steady-state counters unchanged. If <1us: declare
// structural ceiling next round with the arithmetic.

#define RR 32
#define DD 1024
#define HH 128
#define OO 64
#define TROWS 64
#define TILES 8
#define BLOCKS_PER_R 16

#define SHP 136   // u16 stride, h planes [row][feat]
#define SXG 40    // u16 stride, xg plane [row][feat]
#define SSC 136   // u16 stride, weight staging / wout_lds [col][k], K=128
#define SW1 40    // u16 stride, W1 scratch [col][k], K=32

typedef _Float16 f16x8_t __attribute__((ext_vector_type(8)));
typedef float f32x4_t __attribute__((ext_vector_type(4)));
typedef unsigned short u16;
typedef unsigned int u32;

__device__ __forceinline__ u32 pkrtz(float a, float b) {
    union { __fp16 v __attribute__((ext_vector_type(2))); u32 u; } c;
    c.v = __builtin_amdgcn_cvt_pkrtz(a, b);
    return c.u;
}
__device__ __forceinline__ f32x4_t mfma16h(f16x8_t a, f16x8_t b, f32x4_t c) {
    return __builtin_amdgcn_mfma_f32_16x16x32_f16(a, b, c, 0, 0, 0);
}

// stage [K x 32] weight slice (row-major [k][col], ld ldc, col offset c0) into
// fp16 [col][k] dst (k-stride sd), conflict-free 4x4 transpose.
// tp in [0, 8*K/4): cb = tp&7 (col quad), kb = tp>>3 (k quad).
__device__ __forceinline__ void stage_block16(const float* __restrict__ W,
                                              const int* __restrict__ M,
                                              int ldc, int c0, int K,
                                              u16* dst, int sd, int tp)
{
    const int kb = tp >> 3;
    const int cb = tp & 7;
    if (kb * 4 >= K) return;
    const int k0 = kb * 4;
    float e[4][4];
#pragma unroll
    for (int i = 0; i < 4; ++i) {
        const int o = ((k0 + i) * ldc + c0 + 4 * cb) >> 2;
        float4 w = ((const float4*)W)[o];
        int4   m = ((const int4*)M)[o];
        e[i][0] = m.x ? w.x : 0.f; e[i][1] = m.y ? w.y : 0.f;
        e[i][2] = m.z ? w.z : 0.f; e[i][3] = m.w ? w.w : 0.f;
    }
#pragma unroll
    for (int j = 0; j < 4; ++j) {
        uint2 p;
        p.x = pkrtz(e[0][j], e[1][j]);
        p.y = pkrtz(e[2][j], e[3][j]);
        *(uint2*)&dst[(4 * cb + j) * sd + k0] = p;
    }
}

// ReLU + fp16 pack of 4 accumulator values, one 8B store.
__device__ __forceinline__ void relu_store16(u16* __restrict__ dst, int o, f32x4_t a)
{
    uint2 s;
    s.x = pkrtz(fmaxf(a[0], 0.f), fmaxf(a[1], 0.f));
    s.y = pkrtz(fmaxf(a[2], 0.f), fmaxf(a[3], 0.f));
    *(uint2*)&dst[o] = s;
}

__global__ __launch_bounds__(512, 4)
void made_flow_r27(const float* __restrict__ inputs,
                   const float* __restrict__ W1,
                   const float* __restrict__ W2,
                   const float* __restrict__ Wout,
                   const int* __restrict__ idx,
                   const int* __restrict__ valid,
                   const int* __restrict__ M1,
                   const int* __restrict__ M2,
                   const int* __restrict__ Mout,
                   float* __restrict__ out)
{
    __shared__ __align__(16) u16 h1s[TROWS * SHP];      // 17408 B (staging scratch A)
    __shared__ __align__(16) u16 h2s[TROWS * SHP];      // 17408 B (staging scratch B)
    __shared__ __align__(16) u16 wout_lds[OO * SSC];    // 17408 B (Wout^T resident)
    __shared__ __align__(16) u16 xgh[2][TROWS * SXG];   // 10240 B (also W1 scratch)
    __shared__ __align__(16) float red2[2][TROWS][4];   // 2048 B
    // total 64512 B -> 2 blocks/CU

    u16* const scr  = h1s;
    u16* const scr2 = h2s;
    u16* const xw1  = &xgh[0][0];   // W1 scratch: 128 cols x SW1 = 5120 u16 (both planes)

    const int tid  = threadIdx.x;
    const int r    = blockIdx.x / BLOCKS_PER_R;
    const int rb   = blockIdx.x % BLOCKS_PER_R;
    const int ts64 = rb * TILES * TROWS;     // first batch row of this block

    const int lane = tid & 63;
    const int wave = tid >> 6;     // 0..7
    const int q    = lane >> 4;
    const int l16  = lane & 15;
    const int mq   = wave & 3;     // P1/P2: col group 32*mq
    const int nh   = wave >> 2;    // P1/P2: ni pair {2nh, 2nh+1}
    const int wm3  = wave & 3;     // P3: o-col group 16*wm3
    const int ni3  = wave >> 2;    // P3: batch-row quarter base (ni3, ni3+2)

    // ---- per-lane metadata straight from global (no LDS arrays) ----
    const int grow = tid >> 4;     // 0..31 (gather rows grow, grow+32)
    const int gg   = tid & 15;     // col pair: 2*gg, 2*gg+1
    const int   ci0 = idx[r * RR + 2 * gg];
    const int   ci1 = idx[r * RR + 2 * gg + 1];
    const float cv0 = valid[r * RR + 2 * gg]     ? 1.f : 0.f;
    const float cv1 = valid[r * RR + 2 * gg + 1] ? 1.f : 0.f;
    const int j0  = 8 * wm3 + 2 * q;                    // epilogue cols
    const float vj0 = valid[r * RR + j0]     ? 1.f : 0.f;
    const float vj1 = valid[r * RR + j0 + 1] ? 1.f : 0.f;
    const int gb0 = (ts64 + grow) * DD;
    const int gb1 = (ts64 + 32 + grow) * DD;

    // ---- issue gather(0) and gather(1) NOW: latency hides under preamble ----
    float g0[4], gx[4];
    g0[0] = inputs[gb0 + ci0] * cv0;
    g0[1] = inputs[gb0 + ci1] * cv1;
    g0[2] = inputs[gb1 + ci0] * cv0;
    g0[3] = inputs[gb1 + ci1] * cv1;
    gx[0] = inputs[gb0 + TROWS * DD + ci0] * cv0;
    gx[1] = inputs[gb0 + TROWS * DD + ci1] * cv1;
    gx[2] = inputs[gb1 + TROWS * DD + ci0] * cv0;
    gx[3] = inputs[gb1 + TROWS * DD + ci1] * cv1;

    // ---- compact 6-barrier preamble ----
    f16x8_t a1[2];      // W1^T: cols 32mq+16mi+l16, k=q*8..
    f16x8_t a2[2][4];   // W2^T: [mi][ks], cols 32mq+16mi+l16
    {
        const float* W1r = W1 + r * RR * HH;   const int* M1r = M1 + r * RR * HH;
        const float* W2r = W2 + r * HH * HH;   const int* M2r = M2 + r * HH * HH;
        const float* Wor = Wout + r * HH * OO; const int* Mor = Mout + r * HH * OO;

        // R1: stage W2 chunks 0,1
        if (tid < 256) stage_block16(W2r, M2r, HH, 0,  HH, scr,  SSC, tid);
        else           stage_block16(W2r, M2r, HH, 32, HH, scr2, SSC, tid - 256);
        __syncthreads();   // (1)
        // R2: extract a2 for mq 0,1  ||  stage Wout -> wout_lds (disjoint LDS)
        if (mq == 0) {
#pragma unroll
            for (int mi = 0; mi < 2; ++mi)
#pragma unroll
                for (int ks = 0; ks < 4; ++ks)
                    a2[mi][ks] = *(const f16x8_t*)&scr[(16 * mi + l16) * SSC + ks * 32 + q * 8];
        } else if (mq == 1) {
#pragma unroll
            for (int mi = 0; mi < 2; ++mi)
#pragma unroll
                for (int ks = 0; ks < 4; ++ks)
                    a2[mi][ks] = *(const f16x8_t*)&scr2[(16 * mi + l16) * SSC + ks * 32 + q * 8];
        }
        if (tid < 256) stage_block16(Wor, Mor, OO, 0,  HH, wout_lds,            SSC, tid);
        else           stage_block16(Wor, Mor, OO, 32, HH, wout_lds + 32 * SSC, SSC, tid - 256);
        __syncthreads();   // (2)
        // R3: stage W2 chunks 2,3 (overwrites scr/scr2)
        if (tid < 256) stage_block16(W2r, M2r, HH, 64, HH, scr,  SSC, tid);
        else           stage_block16(W2r, M2r, HH, 96, HH, scr2, SSC, tid - 256);
        __syncthreads();   // (3)
        // R4: extract a2 for mq 2,3  ||  stage W1 (4 chunks x 64 threads) -> xw1
        if (mq == 2) {
#pragma unroll
            for (int mi = 0; mi < 2; ++mi)
#pragma unroll
                for (int ks = 0; ks < 4; ++ks)
                    a2[mi][ks] = *(const f16x8_t*)&scr[(16 * mi + l16) * SSC + ks * 32 + q * 8];
        } else if (mq == 3) {
#pragma unroll
            for (int mi = 0; mi < 2; ++mi)
#pragma unroll
                for (int ks = 0; ks < 4; ++ks)
                    a2[mi][ks] = *(const f16x8_t*)&scr2[(16 * mi + l16) * SSC + ks * 32 + q * 8];
        }
        if (tid < 256) {
            const int c  = tid >> 6;        // 0..3
            const int tp = tid & 63;
            stage_block16(W1r, M1r, HH, 32 * c, RR, xw1 + 32 * c * SW1, SW1, tp);
        }
        __syncthreads();   // (4)
        // R5: extract a1 from xw1
#pragma unroll
        for (int mi = 0; mi < 2; ++mi)
            a1[mi] = *(const f16x8_t*)&xw1[(32 * mq + 16 * mi + l16) * SW1 + q * 8];
        __syncthreads();   // (5)  xw1 reads done -> xgh reusable
    }

    const f32x4_t zero4 = {0.f, 0.f, 0.f, 0.f};

    // ---- prologue: store gather(0) -> xgh[0] (loads long since landed) ----
    *(u32*)&xgh[0][grow * SXG + 2 * gg]        = pkrtz(g0[0], g0[1]);
    *(u32*)&xgh[0][(grow + 32) * SXG + 2 * gg] = pkrtz(g0[2], g0[3]);
    __syncthreads();       // (6)

    // ---- prologue: P1(0) -> h1s (M4xN2 split) ----
    {
#pragma unroll
        for (int nn = 0; nn < 2; ++nn) {
            const int rw = 16 * (2 * nh + nn) + l16;
            f16x8_t b = *(const f16x8_t*)&xgh[0][rw * SXG + q * 8];
#pragma unroll
            for (int mi = 0; mi < 2; ++mi) {
                f32x4_t a = mfma16h(a1[mi], b, zero4);
                relu_store16(h1s, rw * SHP + 32 * mq + 16 * mi + 4 * q, a);
            }
        }
    }

    for (int t = 0; t < TILES; ++t) {
        __syncthreads();   // head barrier

        const bool dg = (t + 1 < TILES);

        // ========== interval A: gather-store(t+1) + P2(t) + out-store(t-2) ========
        if (dg) {
            *(u32*)&xgh[(t + 1) & 1][grow * SXG + 2 * gg]        = pkrtz(gx[0], gx[1]);
            *(u32*)&xgh[(t + 1) & 1][(grow + 32) * SXG + 2 * gg] = pkrtz(gx[2], gx[3]);
        }
        {
            // P2(t): wave owns cols 32mq..+32, rows ni=2nh,2nh+1; 16 MFMA, 8 B-reads
            f32x4_t acc[2][2] = {{zero4, zero4}, {zero4, zero4}};
            __builtin_amdgcn_s_setprio(1);
#pragma unroll
            for (int ks = 0; ks < 4; ++ks) {
#pragma unroll
                for (int nn = 0; nn < 2; ++nn) {
                    f16x8_t b = *(const f16x8_t*)&h1s[(16 * (2 * nh + nn) + l16) * SHP + ks * 32 + q * 8];
#pragma unroll
                    for (int mi = 0; mi < 2; ++mi)
                        acc[mi][nn] = mfma16h(a2[mi][ks], b, acc[mi][nn]);
                }
            }
            __builtin_amdgcn_s_setprio(0);
#pragma unroll
            for (int mi = 0; mi < 2; ++mi)
#pragma unroll
                for (int nn = 0; nn < 2; ++nn)
                    relu_store16(h2s, (16 * (2 * nh + nn) + l16) * SHP + 32 * mq + 16 * mi + 4 * q,
                                 acc[mi][nn]);
        }
        if (t >= 2 && tid < TROWS) {
            float4 rv = *(const float4*)&red2[t & 1][tid][0];
            out[((rb * TILES + (t - 2)) * TROWS + tid) * RR + r] =
                rv.x + rv.y + rv.z + rv.w;
        }
        __syncthreads();   // mid barrier

        // ========== interval B: gather-issue(t+2) + P3(t) + P1(t+1) + epilogue(t) ==
        if (t + 2 < TILES) {
            const int base = (t + 2) * (TROWS * DD);
            gx[0] = inputs[gb0 + base + ci0] * cv0;
            gx[1] = inputs[gb0 + base + ci1] * cv1;
            gx[2] = inputs[gb1 + base + ci0] * cv0;
            gx[3] = inputs[gb1 + base + ci1] * cv1;
        }

        // epilogue x reads hoisted above P3 (LDS latency cover)
        u32 xw[2];
#pragma unroll
        for (int nn = 0; nn < 2; ++nn)
            xw[nn] = *(const u32*)&xgh[t & 1][(16 * (ni3 + 2 * nn) + l16) * SXG + j0];

        // P3(t): wave (wm3,ni3): o=16*wm3+4q+i, rows 16*(ni3+2*nn)+l16
        f32x4_t acc3[2] = {zero4, zero4};
        __builtin_amdgcn_s_setprio(1);
#pragma unroll
        for (int ks = 0; ks < 4; ++ks) {
            f16x8_t ao = *(const f16x8_t*)&wout_lds[(16 * wm3 + l16) * SSC + ks * 32 + q * 8];
#pragma unroll
            for (int nn = 0; nn < 2; ++nn) {
                f16x8_t b = *(const f16x8_t*)&h2s[(16 * (ni3 + 2 * nn) + l16) * SHP + ks * 32 + q * 8];
                acc3[nn] = mfma16h(ao, b, acc3[nn]);
            }
        }
        __builtin_amdgcn_s_setprio(0);

        if (dg) {   // P1(t+1): M4xN2 split
#pragma unroll
            for (int nn = 0; nn < 2; ++nn) {
                const int rw = 16 * (2 * nh + nn) + l16;
                f16x8_t b = *(const f16x8_t*)&xgh[(t + 1) & 1][rw * SXG + q * 8];
#pragma unroll
                for (int mi = 0; mi < 2; ++mi) {
                    f32x4_t a = mfma16h(a1[mi], b, zero4);
                    relu_store16(h1s, rw * SHP + 32 * mq + 16 * mi + 4 * q, a);
                }
            }
        }

        // epilogue(t): acc3[nn][i]: i even=shift(j), i odd=log_s(j), j=8*wm3+2q+(i>>1)
#pragma unroll
        for (int nn = 0; nn < 2; ++nn) {
            const int row = 16 * (ni3 + 2 * nn) + l16;
            union { u32 u; _Float16 h[2]; } xc; xc.u = xw[nn];
            const float xv0 = (float)xc.h[0], xv1 = (float)xc.h[1];
            f32x4_t a = acc3[nn];
            const float u0 = (xv0 - a[0]) * __expf(-a[1]);
            const float u1 = (xv1 - a[2]) * __expf(-a[3]);
            float p = (-0.5f * u0 * u0 - 0.91893853320467266954f - a[1]) * vj0
                    + (-0.5f * u1 * u1 - 0.91893853320467266954f - a[3]) * vj1;
            p += __shfl_xor(p, 16, 64);
            p += __shfl_xor(p, 32, 64);
            if (q == 0) red2[t & 1][row][wm3] = p;
        }
    }

    // ---- tail: store tiles TILES-2 and TILES-1 ----
    __syncthreads();
    if (tid < 2 * TROWS) {
        const int tt  = TILES - 2 + (tid >> 6);
        const int row = tid & 63;
        float4 rv = *(const float4*)&red2[tt & 1][row][0];
        out[((rb * TILES + tt) * TROWS + row) * RR + r] =
            rv.x + rv.y + rv.z + rv.w;
    }
}

extern "C" void kernel_launch(void* const* d_in, const int* in_sizes, int n_in,
                              void* d_out, int out_size, void* d_ws, size_t ws_size,
                              hipStream_t stream)
{
    const float* inputs = (const float*)d_in[0];
    const float* W1     = (const float*)d_in[1];
    const float* W2     = (const float*)d_in[2];
    const float* Wout   = (const float*)d_in[3];
    const int*   idx    = (const int*)d_in[4];
    const int*   valid  = (const int*)d_in[5];
    const int*   M1     = (const int*)d_in[6];
    const int*   M2     = (const int*)d_in[7];
    const int*   Mout   = (const int*)d_in[8];
    float*       out    = (float*)d_out;

    hipLaunchKernelGGL(made_flow_r27, dim3(RR * BLOCKS_PER_R), dim3(512), 0, stream,
                       inputs, W1, W2, Wout, idx, valid, M1, M2, Mout, out);
}

// Round 19
// 115.929 us; speedup vs baseline: 1.0503x; 1.0097x over previous
//
#include <hip/hip_runtime.h>
#include <math.h>

// AutoregressiveFlowLayer MI355X — round 28.
// R27 post-mortem (43.2/42.6us): preamble compaction Δ<=1us -> overhead wasn't
// on the critical path. 18-variant ledger complete: every axis (barriers,
// quantum, grid, occupancy, specialization, barrierless, precision, packing,
// prefetch, preamble) lands 43-66us; floor ~43. MFMA floor 6us, HBM floor
// 7.2us; LDS layout re-verified bank-minimal (8 accesses/bank = b128 wave64
// minimum). The binding constraint is the 3-layer dependent chain x 16-waves/CU
// TLP cap (128-reg bin).
// R28 = FINAL isolated A/B: R27 minus s_setprio. setprio entered R24 bundled
// with the M4xN2 split, never isolated; m190 says setprio in barrier-lockstep
// GEMM is null-to-NEGATIVE (boosting MFMA waves delays the co-resident block's
// issue phases — both blocks interleave on the same SIMDs). Single change,
// byte-identical otherwise.
// Predict: if m190 transfers 43 -> 41.5-43; if not 43 -> 44-45 (keep R27).
// Either way: declare the structural ceiling after this round.

#define RR 32
#define DD 1024
#define HH 128
#define OO 64
#define TROWS 64
#define TILES 8
#define BLOCKS_PER_R 16

#define SHP 136   // u16 stride, h planes [row][feat]
#define SXG 40    // u16 stride, xg plane [row][feat]
#define SSC 136   // u16 stride, weight staging / wout_lds [col][k], K=128
#define SW1 40    // u16 stride, W1 scratch [col][k], K=32

typedef _Float16 f16x8_t __attribute__((ext_vector_type(8)));
typedef float f32x4_t __attribute__((ext_vector_type(4)));
typedef unsigned short u16;
typedef unsigned int u32;

__device__ __forceinline__ u32 pkrtz(float a, float b) {
    union { __fp16 v __attribute__((ext_vector_type(2))); u32 u; } c;
    c.v = __builtin_amdgcn_cvt_pkrtz(a, b);
    return c.u;
}
__device__ __forceinline__ f32x4_t mfma16h(f16x8_t a, f16x8_t b, f32x4_t c) {
    return __builtin_amdgcn_mfma_f32_16x16x32_f16(a, b, c, 0, 0, 0);
}

// stage [K x 32] weight slice (row-major [k][col], ld ldc, col offset c0) into
// fp16 [col][k] dst (k-stride sd), conflict-free 4x4 transpose.
__device__ __forceinline__ void stage_block16(const float* __restrict__ W,
                                              const int* __restrict__ M,
                                              int ldc, int c0, int K,
                                              u16* dst, int sd, int tp)
{
    const int kb = tp >> 3;
    const int cb = tp & 7;
    if (kb * 4 >= K) return;
    const int k0 = kb * 4;
    float e[4][4];
#pragma unroll
    for (int i = 0; i < 4; ++i) {
        const int o = ((k0 + i) * ldc + c0 + 4 * cb) >> 2;
        float4 w = ((const float4*)W)[o];
        int4   m = ((const int4*)M)[o];
        e[i][0] = m.x ? w.x : 0.f; e[i][1] = m.y ? w.y : 0.f;
        e[i][2] = m.z ? w.z : 0.f; e[i][3] = m.w ? w.w : 0.f;
    }
#pragma unroll
    for (int j = 0; j < 4; ++j) {
        uint2 p;
        p.x = pkrtz(e[0][j], e[1][j]);
        p.y = pkrtz(e[2][j], e[3][j]);
        *(uint2*)&dst[(4 * cb + j) * sd + k0] = p;
    }
}

// ReLU + fp16 pack of 4 accumulator values, one 8B store.
__device__ __forceinline__ void relu_store16(u16* __restrict__ dst, int o, f32x4_t a)
{
    uint2 s;
    s.x = pkrtz(fmaxf(a[0], 0.f), fmaxf(a[1], 0.f));
    s.y = pkrtz(fmaxf(a[2], 0.f), fmaxf(a[3], 0.f));
    *(uint2*)&dst[o] = s;
}

__global__ __launch_bounds__(512, 4)
void made_flow_r28(const float* __restrict__ inputs,
                   const float* __restrict__ W1,
                   const float* __restrict__ W2,
                   const float* __restrict__ Wout,
                   const int* __restrict__ idx,
                   const int* __restrict__ valid,
                   const int* __restrict__ M1,
                   const int* __restrict__ M2,
                   const int* __restrict__ Mout,
                   float* __restrict__ out)
{
    __shared__ __align__(16) u16 h1s[TROWS * SHP];      // 17408 B (staging scratch A)
    __shared__ __align__(16) u16 h2s[TROWS * SHP];      // 17408 B (staging scratch B)
    __shared__ __align__(16) u16 wout_lds[OO * SSC];    // 17408 B (Wout^T resident)
    __shared__ __align__(16) u16 xgh[2][TROWS * SXG];   // 10240 B (also W1 scratch)
    __shared__ __align__(16) float red2[2][TROWS][4];   // 2048 B
    // total 64512 B -> 2 blocks/CU

    u16* const scr  = h1s;
    u16* const scr2 = h2s;
    u16* const xw1  = &xgh[0][0];   // W1 scratch: 128 cols x SW1

    const int tid  = threadIdx.x;
    const int r    = blockIdx.x / BLOCKS_PER_R;
    const int rb   = blockIdx.x % BLOCKS_PER_R;
    const int ts64 = rb * TILES * TROWS;

    const int lane = tid & 63;
    const int wave = tid >> 6;     // 0..7
    const int q    = lane >> 4;
    const int l16  = lane & 15;
    const int mq   = wave & 3;     // P1/P2: col group 32*mq
    const int nh   = wave >> 2;    // P1/P2: ni pair {2nh, 2nh+1}
    const int wm3  = wave & 3;     // P3: o-col group 16*wm3
    const int ni3  = wave >> 2;    // P3: batch-row quarter base (ni3, ni3+2)

    // ---- per-lane metadata straight from global ----
    const int grow = tid >> 4;     // 0..31 (gather rows grow, grow+32)
    const int gg   = tid & 15;     // col pair: 2*gg, 2*gg+1
    const int   ci0 = idx[r * RR + 2 * gg];
    const int   ci1 = idx[r * RR + 2 * gg + 1];
    const float cv0 = valid[r * RR + 2 * gg]     ? 1.f : 0.f;
    const float cv1 = valid[r * RR + 2 * gg + 1] ? 1.f : 0.f;
    const int j0  = 8 * wm3 + 2 * q;                    // epilogue cols
    const float vj0 = valid[r * RR + j0]     ? 1.f : 0.f;
    const float vj1 = valid[r * RR + j0 + 1] ? 1.f : 0.f;
    const int gb0 = (ts64 + grow) * DD;
    const int gb1 = (ts64 + 32 + grow) * DD;

    // ---- issue gather(0) and gather(1) NOW: latency hides under preamble ----
    float g0[4], gx[4];
    g0[0] = inputs[gb0 + ci0] * cv0;
    g0[1] = inputs[gb0 + ci1] * cv1;
    g0[2] = inputs[gb1 + ci0] * cv0;
    g0[3] = inputs[gb1 + ci1] * cv1;
    gx[0] = inputs[gb0 + TROWS * DD + ci0] * cv0;
    gx[1] = inputs[gb0 + TROWS * DD + ci1] * cv1;
    gx[2] = inputs[gb1 + TROWS * DD + ci0] * cv0;
    gx[3] = inputs[gb1 + TROWS * DD + ci1] * cv1;

    // ---- compact 6-barrier preamble ----
    f16x8_t a1[2];      // W1^T: cols 32mq+16mi+l16, k=q*8..
    f16x8_t a2[2][4];   // W2^T: [mi][ks], cols 32mq+16mi+l16
    {
        const float* W1r = W1 + r * RR * HH;   const int* M1r = M1 + r * RR * HH;
        const float* W2r = W2 + r * HH * HH;   const int* M2r = M2 + r * HH * HH;
        const float* Wor = Wout + r * HH * OO; const int* Mor = Mout + r * HH * OO;

        // R1: stage W2 chunks 0,1
        if (tid < 256) stage_block16(W2r, M2r, HH, 0,  HH, scr,  SSC, tid);
        else           stage_block16(W2r, M2r, HH, 32, HH, scr2, SSC, tid - 256);
        __syncthreads();   // (1)
        // R2: extract a2 for mq 0,1  ||  stage Wout -> wout_lds
        if (mq == 0) {
#pragma unroll
            for (int mi = 0; mi < 2; ++mi)
#pragma unroll
                for (int ks = 0; ks < 4; ++ks)
                    a2[mi][ks] = *(const f16x8_t*)&scr[(16 * mi + l16) * SSC + ks * 32 + q * 8];
        } else if (mq == 1) {
#pragma unroll
            for (int mi = 0; mi < 2; ++mi)
#pragma unroll
                for (int ks = 0; ks < 4; ++ks)
                    a2[mi][ks] = *(const f16x8_t*)&scr2[(16 * mi + l16) * SSC + ks * 32 + q * 8];
        }
        if (tid < 256) stage_block16(Wor, Mor, OO, 0,  HH, wout_lds,            SSC, tid);
        else           stage_block16(Wor, Mor, OO, 32, HH, wout_lds + 32 * SSC, SSC, tid - 256);
        __syncthreads();   // (2)
        // R3: stage W2 chunks 2,3
        if (tid < 256) stage_block16(W2r, M2r, HH, 64, HH, scr,  SSC, tid);
        else           stage_block16(W2r, M2r, HH, 96, HH, scr2, SSC, tid - 256);
        __syncthreads();   // (3)
        // R4: extract a2 for mq 2,3  ||  stage W1 -> xw1
        if (mq == 2) {
#pragma unroll
            for (int mi = 0; mi < 2; ++mi)
#pragma unroll
                for (int ks = 0; ks < 4; ++ks)
                    a2[mi][ks] = *(const f16x8_t*)&scr[(16 * mi + l16) * SSC + ks * 32 + q * 8];
        } else if (mq == 3) {
#pragma unroll
            for (int mi = 0; mi < 2; ++mi)
#pragma unroll
                for (int ks = 0; ks < 4; ++ks)
                    a2[mi][ks] = *(const f16x8_t*)&scr2[(16 * mi + l16) * SSC + ks * 32 + q * 8];
        }
        if (tid < 256) {
            const int c  = tid >> 6;        // 0..3
            const int tp = tid & 63;
            stage_block16(W1r, M1r, HH, 32 * c, RR, xw1 + 32 * c * SW1, SW1, tp);
        }
        __syncthreads();   // (4)
        // R5: extract a1 from xw1
#pragma unroll
        for (int mi = 0; mi < 2; ++mi)
            a1[mi] = *(const f16x8_t*)&xw1[(32 * mq + 16 * mi + l16) * SW1 + q * 8];
        __syncthreads();   // (5)
    }

    const f32x4_t zero4 = {0.f, 0.f, 0.f, 0.f};

    // ---- prologue: store gather(0) -> xgh[0] ----
    *(u32*)&xgh[0][grow * SXG + 2 * gg]        = pkrtz(g0[0], g0[1]);
    *(u32*)&xgh[0][(grow + 32) * SXG + 2 * gg] = pkrtz(g0[2], g0[3]);
    __syncthreads();       // (6)

    // ---- prologue: P1(0) -> h1s (M4xN2 split) ----
    {
#pragma unroll
        for (int nn = 0; nn < 2; ++nn) {
            const int rw = 16 * (2 * nh + nn) + l16;
            f16x8_t b = *(const f16x8_t*)&xgh[0][rw * SXG + q * 8];
#pragma unroll
            for (int mi = 0; mi < 2; ++mi) {
                f32x4_t a = mfma16h(a1[mi], b, zero4);
                relu_store16(h1s, rw * SHP + 32 * mq + 16 * mi + 4 * q, a);
            }
        }
    }

    for (int t = 0; t < TILES; ++t) {
        __syncthreads();   // head barrier

        const bool dg = (t + 1 < TILES);

        // ========== interval A: gather-store(t+1) + P2(t) + out-store(t-2) ========
        if (dg) {
            *(u32*)&xgh[(t + 1) & 1][grow * SXG + 2 * gg]        = pkrtz(gx[0], gx[1]);
            *(u32*)&xgh[(t + 1) & 1][(grow + 32) * SXG + 2 * gg] = pkrtz(gx[2], gx[3]);
        }
        {
            // P2(t): wave owns cols 32mq..+32, rows ni=2nh,2nh+1; 16 MFMA, 8 B-reads
            f32x4_t acc[2][2] = {{zero4, zero4}, {zero4, zero4}};
#pragma unroll
            for (int ks = 0; ks < 4; ++ks) {
#pragma unroll
                for (int nn = 0; nn < 2; ++nn) {
                    f16x8_t b = *(const f16x8_t*)&h1s[(16 * (2 * nh + nn) + l16) * SHP + ks * 32 + q * 8];
#pragma unroll
                    for (int mi = 0; mi < 2; ++mi)
                        acc[mi][nn] = mfma16h(a2[mi][ks], b, acc[mi][nn]);
                }
            }
#pragma unroll
            for (int mi = 0; mi < 2; ++mi)
#pragma unroll
                for (int nn = 0; nn < 2; ++nn)
                    relu_store16(h2s, (16 * (2 * nh + nn) + l16) * SHP + 32 * mq + 16 * mi + 4 * q,
                                 acc[mi][nn]);
        }
        if (t >= 2 && tid < TROWS) {
            float4 rv = *(const float4*)&red2[t & 1][tid][0];
            out[((rb * TILES + (t - 2)) * TROWS + tid) * RR + r] =
                rv.x + rv.y + rv.z + rv.w;
        }
        __syncthreads();   // mid barrier

        // ========== interval B: gather-issue(t+2) + P3(t) + P1(t+1) + epilogue(t) ==
        if (t + 2 < TILES) {
            const int base = (t + 2) * (TROWS * DD);
            gx[0] = inputs[gb0 + base + ci0] * cv0;
            gx[1] = inputs[gb0 + base + ci1] * cv1;
            gx[2] = inputs[gb1 + base + ci0] * cv0;
            gx[3] = inputs[gb1 + base + ci1] * cv1;
        }

        // epilogue x reads hoisted above P3
        u32 xw[2];
#pragma unroll
        for (int nn = 0; nn < 2; ++nn)
            xw[nn] = *(const u32*)&xgh[t & 1][(16 * (ni3 + 2 * nn) + l16) * SXG + j0];

        // P3(t): wave (wm3,ni3): o=16*wm3+4q+i, rows 16*(ni3+2*nn)+l16
        f32x4_t acc3[2] = {zero4, zero4};
#pragma unroll
        for (int ks = 0; ks < 4; ++ks) {
            f16x8_t ao = *(const f16x8_t*)&wout_lds[(16 * wm3 + l16) * SSC + ks * 32 + q * 8];
#pragma unroll
            for (int nn = 0; nn < 2; ++nn) {
                f16x8_t b = *(const f16x8_t*)&h2s[(16 * (ni3 + 2 * nn) + l16) * SHP + ks * 32 + q * 8];
                acc3[nn] = mfma16h(ao, b, acc3[nn]);
            }
        }

        if (dg) {   // P1(t+1): M4xN2 split
#pragma unroll
            for (int nn = 0; nn < 2; ++nn) {
                const int rw = 16 * (2 * nh + nn) + l16;
                f16x8_t b = *(const f16x8_t*)&xgh[(t + 1) & 1][rw * SXG + q * 8];
#pragma unroll
                for (int mi = 0; mi < 2; ++mi) {
                    f32x4_t a = mfma16h(a1[mi], b, zero4);
                    relu_store16(h1s, rw * SHP + 32 * mq + 16 * mi + 4 * q, a);
                }
            }
        }

        // epilogue(t): acc3[nn][i]: i even=shift(j), i odd=log_s(j), j=8*wm3+2q+(i>>1)
#pragma unroll
        for (int nn = 0; nn < 2; ++nn) {
            const int row = 16 * (ni3 + 2 * nn) + l16;
            union { u32 u; _Float16 h[2]; } xc; xc.u = xw[nn];
            const float xv0 = (float)xc.h[0], xv1 = (float)xc.h[1];
            f32x4_t a = acc3[nn];
            const float u0 = (xv0 - a[0]) * __expf(-a[1]);
            const float u1 = (xv1 - a[2]) * __expf(-a[3]);
            float p = (-0.5f * u0 * u0 - 0.91893853320467266954f - a[1]) * vj0
                    + (-0.5f * u1 * u1 - 0.91893853320467266954f - a[3]) * vj1;
            p += __shfl_xor(p, 16, 64);
            p += __shfl_xor(p, 32, 64);
            if (q == 0) red2[t & 1][row][wm3] = p;
        }
    }

    // ---- tail: store tiles TILES-2 and TILES-1 ----
    __syncthreads();
    if (tid < 2 * TROWS) {
        const int tt  = TILES - 2 + (tid >> 6);
        const int row = tid & 63;
        float4 rv = *(const float4*)&red2[tt & 1][row][0];
        out[((rb * TILES + tt) * TROWS + row) * RR + r] =
            rv.x + rv.y + rv.z + rv.w;
    }
}

extern "C" void kernel_launch(void* const* d_in, const int* in_sizes, int n_in,
                              void* d_out, int out_size, void* d_ws, size_t ws_size,
                              hipStream_t stream)
{
    const float* inputs = (const float*)d_in[0];
    const float* W1     = (const float*)d_in[1];
    const float* W2     = (const float*)d_in[2];
    const float* Wout   = (const float*)d_in[3];
    const int*   idx    = (const int*)d_in[4];
    const int*   valid  = (const int*)d_in[5];
    const int*   M1     = (const int*)d_in[6];
    const int*   M2     = (const int*)d_in[7];
    const int*   Mout   = (const int*)d_in[8];
    float*       out    = (float*)d_out;

    hipLaunchKernelGGL(made_flow_r28, dim3(RR * BLOCKS_PER_R), dim3(512), 0, stream,
                       inputs, W1, W2, Wout, idx, valid, M1, M2, Mout, out);
}